// Round 3
// baseline (1128.456 us; speedup 1.0000x reference)
//
#include <hip/hip_runtime.h>

// GraphSAGE 3-layer, mean aggregator, eval mode.
// Pipeline per call:
//   1. deg[dst]++ (atomics)                     -- counting-sort CSR build
//   2. row_ptr = exclusive-scan(deg)            -- single-block scan
//   3. src_sorted[atomicAdd(cursor[dst])] = src -- scatter edges by dst
//   4. 3x { aggregate (wave-per-node, CSR), fused GEMM h@Ws + agg@Wn + b (+ReLU) }

// ---------------------------------------------------------------- CSR build
__global__ __launch_bounds__(256) void deg_kernel(const int* __restrict__ dst,
                                                  int* __restrict__ deg, int n_edges) {
  int i = blockIdx.x * 256 + threadIdx.x;
  if (i < n_edges) atomicAdd(&deg[dst[i]], 1);
}

__global__ __launch_bounds__(1024) void scan_kernel(const int* __restrict__ deg,
                                                    int* __restrict__ row_ptr,
                                                    int* __restrict__ cursor, int n) {
  __shared__ int buf[1024];
  __shared__ int carry_s;
  int tid = threadIdx.x;
  if (tid == 0) { carry_s = 0; row_ptr[0] = 0; }
  __syncthreads();
  for (int base = 0; base < n; base += 1024) {
    int i = base + tid;
    int v = (i < n) ? deg[i] : 0;
    int x = v;
    buf[tid] = x;
    __syncthreads();
#pragma unroll
    for (int off = 1; off < 1024; off <<= 1) {
      int t = (tid >= off) ? buf[tid - off] : 0;
      __syncthreads();
      x += t;
      buf[tid] = x;
      __syncthreads();
    }
    int c = carry_s;
    if (i < n) {
      row_ptr[i + 1] = c + x;      // inclusive prefix through i
      cursor[i] = c + x - v;       // exclusive prefix = row start
    }
    __syncthreads();
    if (tid == 1023) carry_s += x; // x of tid 1023 == chunk total
    __syncthreads();
  }
}

__global__ __launch_bounds__(256) void scatter_kernel(const int* __restrict__ src,
                                                      const int* __restrict__ dst,
                                                      int* __restrict__ cursor,
                                                      int* __restrict__ src_sorted,
                                                      int n_edges) {
  int i = blockIdx.x * 256 + threadIdx.x;
  if (i < n_edges) {
    int pos = atomicAdd(&cursor[dst[i]], 1);
    src_sorted[pos] = src[i];
  }
}

// ---------------------------------------------------------- mean aggregation
// One wave (64 lanes) per dst node; lane holds float2 -> 128 features.
// Edge gathers: 64 lanes x 8B = 512B contiguous per src row, accumulate in regs.
__global__ __launch_bounds__(256) void aggregate_kernel(
    const float* __restrict__ h, const int* __restrict__ row_ptr,
    const int* __restrict__ src_sorted, const int* __restrict__ deg,
    float* __restrict__ agg, int n) {
  int gid = blockIdx.x * 256 + threadIdx.x;
  int node = gid >> 6;
  int lane = gid & 63;
  if (node >= n) return;
  int beg = row_ptr[node];
  int end = row_ptr[node + 1];
  float ax = 0.f, ay = 0.f;
  int e = beg;
  for (; e + 2 <= end; e += 2) {  // unroll x2: two independent gathers in flight
    int s0 = src_sorted[e];
    int s1 = src_sorted[e + 1];
    float2 v0 = *(const float2*)(h + (size_t)s0 * 128 + lane * 2);
    float2 v1 = *(const float2*)(h + (size_t)s1 * 128 + lane * 2);
    ax += v0.x + v1.x;
    ay += v0.y + v1.y;
  }
  if (e < end) {
    int s0 = src_sorted[e];
    float2 v0 = *(const float2*)(h + (size_t)s0 * 128 + lane * 2);
    ax += v0.x;
    ay += v0.y;
  }
  float inv = 1.0f / fmaxf((float)deg[node], 1.0f);
  float2* out2 = (float2*)(agg + (size_t)node * 128);
  out2[lane] = make_float2(ax * inv, ay * inv);
}

// ------------------------------------------------------------------- GEMM
// out[n][NOUT] = act( X0[n][128] @ W0 + X1[n][128] @ W1 + b )
// Block: 256 thr (4 waves), tile M=64 nodes, full NOUT, K chunked by 64.
// Wave w owns rows [w*16, w*16+16); lane owns CPL=NOUT/64 consecutive cols.
// Xs reads are wave-broadcast (free), Wc reads are lane-consecutive float2.
template <int NOUT, bool RELU>
__global__ __launch_bounds__(256) void gemm_layer(
    const float* __restrict__ X0, const float* __restrict__ X1,
    const float* __restrict__ W0, const float* __restrict__ W1,
    const float* __restrict__ bias, float* __restrict__ out, int n) {
  constexpr int M = 64;
  constexpr int KC = 64;
  constexpr int CPL = NOUT / 64;  // cols per lane: 2 (NOUT=128) or 1 (NOUT=64)
  __shared__ float Xs[M][KC];       // 16 KB
  __shared__ float Wc[KC][NOUT];    // 32 KB (NOUT=128) / 16 KB

  int tid = threadIdx.x;
  int wave = tid >> 6;
  int lane = tid & 63;
  int m0 = blockIdx.x * M;

  float acc[16][CPL];
#pragma unroll
  for (int i = 0; i < 16; ++i)
#pragma unroll
    for (int j = 0; j < CPL; ++j) acc[i][j] = 0.f;

#pragma unroll
  for (int c = 0; c < 4; ++c) {
    const float* X = (c < 2) ? X0 : X1;
    const float* W = (c < 2) ? W0 : W1;
    int koff = (c & 1) * KC;

    // stage X tile: 64 rows x 64 cols = 1024 float4, 4 per thread
#pragma unroll
    for (int i = 0; i < 4; ++i) {
      int l = tid + i * 256;
      int r = l >> 4;
      int c4 = (l & 15) * 4;
      int node = m0 + r;
      float4 v = make_float4(0.f, 0.f, 0.f, 0.f);
      if (node < n) v = *(const float4*)(X + (size_t)node * 128 + koff + c4);
      *(float4*)&Xs[r][c4] = v;
    }
    // stage W chunk: KC x NOUT floats
    constexpr int WLD = (KC * NOUT) / (256 * 4);
#pragma unroll
    for (int i = 0; i < WLD; ++i) {
      int l = tid + i * 256;
      int kk = l / (NOUT / 4);
      int c4 = (l % (NOUT / 4)) * 4;
      float4 v = *(const float4*)(W + (size_t)(koff + kk) * NOUT + c4);
      *(float4*)&Wc[kk][c4] = v;
    }
    __syncthreads();

#pragma unroll 4
    for (int k = 0; k < KC; ++k) {
      float wv[CPL];
      if constexpr (CPL == 2) {
        float2 wt = *(const float2*)&Wc[k][lane * 2];
        wv[0] = wt.x;
        wv[1] = wt.y;
      } else {
        wv[0] = Wc[k][lane];
      }
#pragma unroll
      for (int i = 0; i < 16; ++i) {
        float x = Xs[wave * 16 + i][k];  // wave-uniform broadcast
#pragma unroll
        for (int j = 0; j < CPL; ++j) acc[i][j] = fmaf(x, wv[j], acc[i][j]);
      }
    }
    __syncthreads();
  }

  float bv[CPL];
  if constexpr (CPL == 2) {
    float2 bt = *(const float2*)&bias[lane * 2];
    bv[0] = bt.x;
    bv[1] = bt.y;
  } else {
    bv[0] = bias[lane];
  }
#pragma unroll
  for (int i = 0; i < 16; ++i) {
    int node = m0 + wave * 16 + i;
    if (node < n) {
      float o[CPL];
#pragma unroll
      for (int j = 0; j < CPL; ++j) {
        o[j] = acc[i][j] + bv[j];
        if (RELU) o[j] = fmaxf(o[j], 0.f);
      }
      if constexpr (CPL == 2) {
        *(float2*)&out[(size_t)node * NOUT + lane * 2] = make_float2(o[0], o[1]);
      } else {
        out[(size_t)node * NOUT + lane] = o[0];
      }
    }
  }
}

// ------------------------------------------------------------------ launch
extern "C" void kernel_launch(void* const* d_in, const int* in_sizes, int n_in,
                              void* d_out, int out_size, void* d_ws, size_t ws_size,
                              hipStream_t stream) {
  const float* features = (const float*)d_in[0];
  const int* src = (const int*)d_in[1];
  const int* dst = (const int*)d_in[2];
  const float* Ws0 = (const float*)d_in[3];
  const float* Wn0 = (const float*)d_in[4];
  const float* b0 = (const float*)d_in[5];
  const float* Ws1 = (const float*)d_in[6];
  const float* Wn1 = (const float*)d_in[7];
  const float* b1 = (const float*)d_in[8];
  const float* Ws2 = (const float*)d_in[9];
  const float* Wn2 = (const float*)d_in[10];
  const float* b2 = (const float*)d_in[11];

  const int n = in_sizes[0] / 128;
  const int n_edges = in_sizes[1];

  char* ws = (char*)d_ws;
  size_t off = 0;
  auto alloc = [&](size_t bytes) -> void* {
    void* p = ws + off;
    off += (bytes + 255) & ~(size_t)255;
    return p;
  };
  int* deg = (int*)alloc((size_t)n * 4);
  int* row_ptr = (int*)alloc(((size_t)n + 1) * 4);
  int* cursor = (int*)alloc((size_t)n * 4);
  int* src_sorted = (int*)alloc((size_t)n_edges * 4);
  float* hA = (float*)alloc((size_t)n * 128 * 4);
  float* hB = (float*)alloc((size_t)n * 128 * 4);
  float* agg = (float*)alloc((size_t)n * 128 * 4);

  hipMemsetAsync(deg, 0, (size_t)n * 4, stream);

  int eb = (n_edges + 255) / 256;
  deg_kernel<<<eb, 256, 0, stream>>>(dst, deg, n_edges);
  scan_kernel<<<1, 1024, 0, stream>>>(deg, row_ptr, cursor, n);
  scatter_kernel<<<eb, 256, 0, stream>>>(src, dst, cursor, src_sorted, n_edges);

  int agg_blocks = (int)(((size_t)n * 64 + 255) / 256);
  int gemm_blocks = (n + 63) / 64;

  // layer 0
  aggregate_kernel<<<agg_blocks, 256, 0, stream>>>(features, row_ptr, src_sorted, deg, agg, n);
  gemm_layer<128, true><<<gemm_blocks, 256, 0, stream>>>(features, agg, Ws0, Wn0, b0, hA, n);
  // layer 1
  aggregate_kernel<<<agg_blocks, 256, 0, stream>>>(hA, row_ptr, src_sorted, deg, agg, n);
  gemm_layer<128, true><<<gemm_blocks, 256, 0, stream>>>(hA, agg, Ws1, Wn1, b1, hB, n);
  // layer 2
  aggregate_kernel<<<agg_blocks, 256, 0, stream>>>(hB, row_ptr, src_sorted, deg, agg, n);
  gemm_layer<64, false><<<gemm_blocks, 256, 0, stream>>>(hB, agg, Ws2, Wn2, b2, (float*)d_out, n);
}

// Round 4
// 617.942 us; speedup vs baseline: 1.8262x; 1.8262x over previous
//
#include <hip/hip_runtime.h>

typedef _Float16 f16x8 __attribute__((ext_vector_type(8)));
typedef _Float16 f16x2 __attribute__((ext_vector_type(2)));
typedef float f32x4 __attribute__((ext_vector_type(4)));

// GraphSAGE 3-layer, mean aggregator, eval mode. f16 storage + MFMA GEMM.
// Per call:
//   CSR build: deg atomics -> hierarchical scan (3 kernels) -> scatter
//   features -> f16 into Xcat_A left half; weights -> transposed f16 Wt[NOUT][256]
//   3x { aggregate (wave/node, f16 gather, fp32 acc) ; MFMA GEMM (16x16x32 f16) }
// Xcat layout: [n][256] f16, row = [ h (128) | mean-agg (128) ] -> single K=256 GEMM
// against Wt = [Ws ; Wn]^T. Ping-pong Xcat_A/Xcat_B across layers.

// ---------------------------------------------------------------- CSR build
__global__ __launch_bounds__(256) void deg_kernel(const int* __restrict__ dst,
                                                  int* __restrict__ deg, int n_edges) {
  int i = blockIdx.x * 256 + threadIdx.x;
  if (i < n_edges) atomicAdd(&deg[dst[i]], 1);
}

// block-local inclusive scan (256 elems/block) + block sums
__global__ __launch_bounds__(256) void scan1_kernel(const int* __restrict__ deg,
                                                    int* __restrict__ incl,
                                                    int* __restrict__ bsums, int n) {
  __shared__ int buf[256];
  int tid = threadIdx.x;
  int i = blockIdx.x * 256 + tid;
  int v = (i < n) ? deg[i] : 0;
  int x = v;
  buf[tid] = x;
  __syncthreads();
#pragma unroll
  for (int off = 1; off < 256; off <<= 1) {
    int t = (tid >= off) ? buf[tid - off] : 0;
    __syncthreads();
    x += t;
    buf[tid] = x;
    __syncthreads();
  }
  if (i < n) incl[i] = x;
  if (tid == 255) bsums[blockIdx.x] = x;
}

// single block: exclusive scan of block sums (nb <= 1024)
__global__ __launch_bounds__(1024) void scan2_kernel(int* __restrict__ bsums, int nb) {
  __shared__ int buf[1024];
  int tid = threadIdx.x;
  int v = (tid < nb) ? bsums[tid] : 0;
  int x = v;
  buf[tid] = x;
  __syncthreads();
#pragma unroll
  for (int off = 1; off < 1024; off <<= 1) {
    int t = (tid >= off) ? buf[tid - off] : 0;
    __syncthreads();
    x += t;
    buf[tid] = x;
    __syncthreads();
  }
  if (tid < nb) bsums[tid] = x - v;  // exclusive
}

__global__ __launch_bounds__(256) void scan3_kernel(const int* __restrict__ incl,
                                                    const int* __restrict__ bexcl,
                                                    const int* __restrict__ deg,
                                                    int* __restrict__ row_ptr,
                                                    int* __restrict__ cursor, int n) {
  int i = blockIdx.x * 256 + threadIdx.x;
  if (i < n) {
    int inc = incl[i] + bexcl[i >> 8];
    row_ptr[i + 1] = inc;
    cursor[i] = inc - deg[i];
  }
  if (i == 0) row_ptr[0] = 0;
}

__global__ __launch_bounds__(256) void scatter_kernel(const int* __restrict__ src,
                                                      const int* __restrict__ dst,
                                                      int* __restrict__ cursor,
                                                      int* __restrict__ src_sorted,
                                                      int n_edges) {
  int i = blockIdx.x * 256 + threadIdx.x;
  if (i < n_edges) {
    int pos = atomicAdd(&cursor[dst[i]], 1);
    src_sorted[pos] = src[i];
  }
}

// ------------------------------------------------------- f16 preprocessing
// features f32 [n][128] -> Xcat left half f16 (row stride 256)
__global__ __launch_bounds__(256) void convert_features(const float* __restrict__ f,
                                                        _Float16* __restrict__ X, int n) {
  int idx = blockIdx.x * 256 + threadIdx.x;  // one float4 chunk each
  int total = n * 32;
  if (idx >= total) return;
  int node = idx >> 5;
  int c4 = (idx & 31) * 4;
  float4 v = *(const float4*)(f + (size_t)node * 128 + c4);
  _Float16* o = X + (size_t)node * 256 + c4;
  o[0] = (_Float16)v.x;
  o[1] = (_Float16)v.y;
  o[2] = (_Float16)v.z;
  o[3] = (_Float16)v.w;
}

// Wt[nn][k] = f16( k<128 ? Ws[k][nn] : Wn[k-128][nn] )   (NOUT x 256)
__global__ __launch_bounds__(256) void build_wt(const float* __restrict__ Ws,
                                                const float* __restrict__ Wn,
                                                _Float16* __restrict__ Wt, int NOUT) {
  int idx = blockIdx.x * 256 + threadIdx.x;
  if (idx >= NOUT * 256) return;
  int nn = idx >> 8;
  int k = idx & 255;
  float v = (k < 128) ? Ws[(size_t)k * NOUT + nn] : Wn[(size_t)(k - 128) * NOUT + nn];
  Wt[(size_t)nn * 256 + k] = (_Float16)v;
}

// ---------------------------------------------------------- mean aggregation
// One wave per dst node; lane covers 2 features (f16x2 = 4B). fp32 accumulate.
// Reads Xcat left half (h), writes Xcat right half (agg) of the SAME buffer.
__global__ __launch_bounds__(256) void aggregate_f16(
    const _Float16* __restrict__ X, const int* __restrict__ row_ptr,
    const int* __restrict__ src_sorted, const int* __restrict__ deg,
    _Float16* __restrict__ Xout, int n) {
  int gid = blockIdx.x * 256 + threadIdx.x;
  int node = gid >> 6;
  int lane = gid & 63;
  if (node >= n) return;
  int beg = row_ptr[node];
  int end = row_ptr[node + 1];
  float ax = 0.f, ay = 0.f;
  int e = beg;
  for (; e + 4 <= end; e += 4) {
    int s0 = src_sorted[e + 0];
    int s1 = src_sorted[e + 1];
    int s2 = src_sorted[e + 2];
    int s3 = src_sorted[e + 3];
    f16x2 v0 = *(const f16x2*)(X + (size_t)s0 * 256 + lane * 2);
    f16x2 v1 = *(const f16x2*)(X + (size_t)s1 * 256 + lane * 2);
    f16x2 v2 = *(const f16x2*)(X + (size_t)s2 * 256 + lane * 2);
    f16x2 v3 = *(const f16x2*)(X + (size_t)s3 * 256 + lane * 2);
    ax += (float)v0[0] + (float)v1[0] + (float)v2[0] + (float)v3[0];
    ay += (float)v0[1] + (float)v1[1] + (float)v2[1] + (float)v3[1];
  }
  for (; e < end; ++e) {
    int s0 = src_sorted[e];
    f16x2 v0 = *(const f16x2*)(X + (size_t)s0 * 256 + lane * 2);
    ax += (float)v0[0];
    ay += (float)v0[1];
  }
  float inv = 1.0f / fmaxf((float)deg[node], 1.0f);
  f16x2 o;
  o[0] = (_Float16)(ax * inv);
  o[1] = (_Float16)(ay * inv);
  *(f16x2*)(Xout + (size_t)node * 256 + 128 + lane * 2) = o;
}

// ------------------------------------------------------------------- GEMM
// out[n][NOUT] = act( Xcat[n][256] @ Wt^T + b ), MFMA 16x16x32 f16, fp32 acc.
// Block: 256 thr = 2x2 waves; block tile M=128 x NOUT; wave tile 64 x NOUT/2.
// R=4 x CF col-frags register blocking; K chunked by 64 (4 chunks).
// A frag: lane reads Xs[wr*64 + i*16 + (lane&15)][ks*32 + (lane>>4)*8 ..+8]
// B frag: lane reads Wc[wc*CW + j*16 + (lane&15)][same k]   (Wt is pre-transposed)
// C/D:    row = (lane>>4)*4 + q, col = lane&15   (m89-verified mapping)
template <int NOUT, bool RELU, bool FINAL>
__global__ __launch_bounds__(256) void gemm_mfma(
    const _Float16* __restrict__ X, const _Float16* __restrict__ Wt,
    const float* __restrict__ bias, _Float16* __restrict__ outX,
    float* __restrict__ outF, int n) {
  constexpr int CW = NOUT / 2;   // cols per wave
  constexpr int CF = CW / 16;    // col frags per wave
  __shared__ _Float16 Xs[128][72];    // +8 pad: frag stride 144B -> 2-way max
  __shared__ _Float16 Wc[NOUT][72];

  int tid = threadIdx.x;
  int lane = tid & 63;
  int wid = tid >> 6;
  int wr = wid >> 1;
  int wc = wid & 1;
  int node0 = blockIdx.x * 128;

  f32x4 acc[4][CF];
#pragma unroll
  for (int i = 0; i < 4; ++i)
#pragma unroll
    for (int j = 0; j < CF; ++j) acc[i][j] = {0.f, 0.f, 0.f, 0.f};

#pragma unroll
  for (int c = 0; c < 4; ++c) {
    int k0 = c * 64;
    // stage X chunk: 128 rows x 64 f16 = 1024 x 16B
#pragma unroll
    for (int i = 0; i < 4; ++i) {
      int idx = i * 256 + tid;
      int r = idx >> 3;
      int o = (idx & 7) * 8;
      f16x8 v;
#pragma unroll
      for (int z = 0; z < 8; ++z) v[z] = (_Float16)0.f;
      int node = node0 + r;
      if (node < n) v = *(const f16x8*)(X + (size_t)node * 256 + k0 + o);
      *(f16x8*)&Xs[r][o] = v;
    }
    // stage W chunk: NOUT rows x 64 f16
#pragma unroll
    for (int i = 0; i < NOUT / 32; ++i) {
      int idx = i * 256 + tid;
      int r = idx >> 3;
      int o = (idx & 7) * 8;
      *(f16x8*)&Wc[r][o] = *(const f16x8*)(Wt + (size_t)r * 256 + k0 + o);
    }
    __syncthreads();
#pragma unroll
    for (int ks = 0; ks < 2; ++ks) {
      int kk = ks * 32 + (lane >> 4) * 8;
      f16x8 a[4], b[CF];
#pragma unroll
      for (int i = 0; i < 4; ++i)
        a[i] = *(const f16x8*)&Xs[wr * 64 + i * 16 + (lane & 15)][kk];
#pragma unroll
      for (int j = 0; j < CF; ++j)
        b[j] = *(const f16x8*)&Wc[wc * CW + j * 16 + (lane & 15)][kk];
#pragma unroll
      for (int i = 0; i < 4; ++i)
#pragma unroll
        for (int j = 0; j < CF; ++j)
          acc[i][j] = __builtin_amdgcn_mfma_f32_16x16x32_f16(a[i], b[j], acc[i][j], 0, 0, 0);
    }
    __syncthreads();
  }

  // epilogue
#pragma unroll
  for (int j = 0; j < CF; ++j) {
    int col = wc * CW + j * 16 + (lane & 15);
    float bv = bias[col];
#pragma unroll
    for (int i = 0; i < 4; ++i) {
#pragma unroll
      for (int q = 0; q < 4; ++q) {
        int row = wr * 64 + i * 16 + (lane >> 4) * 4 + q;
        int node = node0 + row;
        if (node < n) {
          float v = acc[i][j][q] + bv;
          if (RELU) v = fmaxf(v, 0.f);
          if (FINAL)
            outF[(size_t)node * NOUT + col] = v;
          else
            outX[(size_t)node * 256 + col] = (_Float16)v;  // left half of next Xcat
        }
      }
    }
  }
}

// ------------------------------------------------------------------ launch
extern "C" void kernel_launch(void* const* d_in, const int* in_sizes, int n_in,
                              void* d_out, int out_size, void* d_ws, size_t ws_size,
                              hipStream_t stream) {
  const float* features = (const float*)d_in[0];
  const int* src = (const int*)d_in[1];
  const int* dst = (const int*)d_in[2];
  const float* Ws0 = (const float*)d_in[3];
  const float* Wn0 = (const float*)d_in[4];
  const float* b0 = (const float*)d_in[5];
  const float* Ws1 = (const float*)d_in[6];
  const float* Wn1 = (const float*)d_in[7];
  const float* b1 = (const float*)d_in[8];
  const float* Ws2 = (const float*)d_in[9];
  const float* Wn2 = (const float*)d_in[10];
  const float* b2 = (const float*)d_in[11];

  const int n = in_sizes[0] / 128;
  const int n_edges = in_sizes[1];

  char* ws = (char*)d_ws;
  size_t off = 0;
  auto alloc = [&](size_t bytes) -> void* {
    void* p = ws + off;
    off += (bytes + 255) & ~(size_t)255;
    return p;
  };
  int* deg = (int*)alloc((size_t)n * 4);
  int* row_ptr = (int*)alloc(((size_t)n + 1) * 4);
  int* cursor = (int*)alloc((size_t)n * 4);
  int* incl = (int*)alloc((size_t)n * 4);
  int* bsums = (int*)alloc(1024 * 4);
  int* src_sorted = (int*)alloc((size_t)n_edges * 4);
  _Float16* XA = (_Float16*)alloc((size_t)n * 256 * 2);
  _Float16* XB = (_Float16*)alloc((size_t)n * 256 * 2);
  _Float16* Wt0 = (_Float16*)alloc((size_t)128 * 256 * 2);
  _Float16* Wt1 = (_Float16*)alloc((size_t)128 * 256 * 2);
  _Float16* Wt2 = (_Float16*)alloc((size_t)64 * 256 * 2);

  hipMemsetAsync(deg, 0, (size_t)n * 4, stream);

  int eb = (n_edges + 255) / 256;
  int nb = (n + 255) / 256;  // 391 for n=100k, fits scan2's 1024
  deg_kernel<<<eb, 256, 0, stream>>>(dst, deg, n_edges);
  scan1_kernel<<<nb, 256, 0, stream>>>(deg, incl, bsums, n);
  scan2_kernel<<<1, 1024, 0, stream>>>(bsums, nb);
  scan3_kernel<<<nb, 256, 0, stream>>>(incl, bsums, deg, row_ptr, cursor, n);
  scatter_kernel<<<eb, 256, 0, stream>>>(src, dst, cursor, src_sorted, n_edges);

  convert_features<<<(n * 32 + 255) / 256, 256, 0, stream>>>(features, XA, n);
  build_wt<<<(128 * 256 + 255) / 256, 256, 0, stream>>>(Ws0, Wn0, Wt0, 128);
  build_wt<<<(128 * 256 + 255) / 256, 256, 0, stream>>>(Ws1, Wn1, Wt1, 128);
  build_wt<<<(64 * 256 + 255) / 256, 256, 0, stream>>>(Ws2, Wn2, Wt2, 64);

  int agg_blocks = (int)(((size_t)n * 64 + 255) / 256);
  int gemm_blocks = (n + 127) / 128;

  // layer 0: Xcat_A = [f16(features) | agg] -> h1 into XB left
  aggregate_f16<<<agg_blocks, 256, 0, stream>>>(XA, row_ptr, src_sorted, deg, XA, n);
  gemm_mfma<128, true, false><<<gemm_blocks, 256, 0, stream>>>(XA, Wt0, b0, XB, nullptr, n);
  // layer 1: XB -> h2 into XA left
  aggregate_f16<<<agg_blocks, 256, 0, stream>>>(XB, row_ptr, src_sorted, deg, XB, n);
  gemm_mfma<128, true, false><<<gemm_blocks, 256, 0, stream>>>(XB, Wt1, b1, XA, nullptr, n);
  // layer 2: XA -> d_out fp32
  aggregate_f16<<<agg_blocks, 256, 0, stream>>>(XA, row_ptr, src_sorted, deg, XA, n);
  gemm_mfma<64, false, true><<<gemm_blocks, 256, 0, stream>>>(XA, Wt2, b2, nullptr, (float*)d_out, n);
}

// Round 5
// 549.264 us; speedup vs baseline: 2.0545x; 1.1250x over previous
//
#include <hip/hip_runtime.h>

typedef _Float16 f16x8 __attribute__((ext_vector_type(8)));
typedef _Float16 f16x2 __attribute__((ext_vector_type(2)));
typedef float f32x4 __attribute__((ext_vector_type(4)));

// GraphSAGE 3-layer, mean aggregator, eval mode. f16 storage + MFMA GEMM.
// CSR build via two-level block-ranged counting sort (no global-cursor scatter):
//   A: per-block LDS histogram over buckets (dst>>7) -> hist_pb[block][bucket]
//   B1: bucket totals  B2: 1-block exclusive scan -> bbase  B3: hist_pb -> offsets
//   C: scatter packed (dstl<<18|src) u32 into bucket-grouped pairs[] (block-local runs)
//   D: block per bucket: LDS hist = deg, LDS scan = row_ptr, scatter src_sorted
//      (random writes confined to the bucket's ~8KB span owned by ONE block)
// Then 3x { aggregate (wave/node, f16 gather, fp32 acc) ; MFMA GEMM 16x16x32 f16 }.
// Xcat layout: [n][256] f16 row = [ h (128) | mean-agg (128) ] -> one K=256 GEMM.

#define BSHIFT 7
#define BSZ 128           // nodes per bucket
#define EPB 16384         // edges per block in passes A/C

// ------------------------------------------------------------- sort pass A
__global__ __launch_bounds__(256) void histA(const int* __restrict__ dst,
                                             int* __restrict__ hist_pb,
                                             int n_edges, int nbk) {
  __shared__ unsigned lh[1024];
  for (int i = threadIdx.x; i < nbk; i += 256) lh[i] = 0;
  __syncthreads();
  int base = blockIdx.x * EPB;
  for (int i = threadIdx.x; i < EPB; i += 256) {
    int e = base + i;
    if (e < n_edges) atomicAdd(&lh[dst[e] >> BSHIFT], 1u);
  }
  __syncthreads();
  for (int i = threadIdx.x; i < nbk; i += 256)
    hist_pb[(size_t)blockIdx.x * nbk + i] = (int)lh[i];
}

// ------------------------------------------------------------- sort pass B
__global__ __launch_bounds__(256) void sumB1(const int* __restrict__ hist_pb,
                                             int* __restrict__ btot, int nblk, int nbk) {
  int b = blockIdx.x * 256 + threadIdx.x;
  if (b >= nbk) return;
  int s = 0;
  for (int k = 0; k < nblk; ++k) s += hist_pb[(size_t)k * nbk + b];
  btot[b] = s;
}

__global__ __launch_bounds__(1024) void scanB2(const int* __restrict__ btot,
                                               int* __restrict__ bbase, int nbk) {
  __shared__ int buf[1024];
  int t = threadIdx.x;
  int v = (t < nbk) ? btot[t] : 0;
  int x = v;
  buf[t] = x;
  __syncthreads();
#pragma unroll
  for (int off = 1; off < 1024; off <<= 1) {
    int tm = (t >= off) ? buf[t - off] : 0;
    __syncthreads();
    x += tm;
    buf[t] = x;
    __syncthreads();
  }
  if (t < nbk) bbase[t] = x - v;          // exclusive
  if (t == nbk - 1) bbase[nbk] = x;       // total edge count
}

__global__ __launch_bounds__(256) void offsB3(int* __restrict__ hist_pb,
                                              const int* __restrict__ bbase,
                                              int nblk, int nbk) {
  int b = blockIdx.x * 256 + threadIdx.x;
  if (b >= nbk) return;
  int run = bbase[b];
  for (int k = 0; k < nblk; ++k) {
    int t = hist_pb[(size_t)k * nbk + b];
    hist_pb[(size_t)k * nbk + b] = run;
    run += t;
  }
}

// ------------------------------------------------------------- sort pass C
__global__ __launch_bounds__(256) void scatC(const int* __restrict__ src,
                                             const int* __restrict__ dst,
                                             const int* __restrict__ hist_pb,
                                             unsigned* __restrict__ pairs,
                                             int n_edges, int nbk) {
  __shared__ unsigned lofs[1024];
  for (int i = threadIdx.x; i < nbk; i += 256)
    lofs[i] = (unsigned)hist_pb[(size_t)blockIdx.x * nbk + i];
  __syncthreads();
  int base = blockIdx.x * EPB;
  for (int i = threadIdx.x; i < EPB; i += 256) {
    int e = base + i;
    if (e < n_edges) {
      int d = dst[e];
      unsigned pos = atomicAdd(&lofs[d >> BSHIFT], 1u);
      pairs[pos] = ((unsigned)(d & (BSZ - 1)) << 18) | (unsigned)src[e];
    }
  }
}

// ------------------------------------------------------------- sort pass D
__global__ __launch_bounds__(256) void finalD(const unsigned* __restrict__ pairs,
                                              const int* __restrict__ bbase,
                                              int* __restrict__ deg,
                                              int* __restrict__ row_ptr,
                                              int* __restrict__ src_sorted,
                                              int n, int nbk) {
  __shared__ int ldeg[BSZ];
  __shared__ int lscan[BSZ];
  __shared__ int lcur[BSZ];
  int b = blockIdx.x;
  int t = threadIdx.x;
  int node0 = b << BSHIFT;
  int beg = bbase[b], end = bbase[b + 1];
  if (t < BSZ) ldeg[t] = 0;
  __syncthreads();
  for (int i = beg + t; i < end; i += 256) atomicAdd(&ldeg[pairs[i] >> 18], 1);
  __syncthreads();
  int x = (t < BSZ) ? ldeg[t] : 0;
  if (t < BSZ) lscan[t] = x;
  __syncthreads();
#pragma unroll
  for (int off = 1; off < BSZ; off <<= 1) {
    int tm = (t >= off && t < BSZ) ? lscan[t - off] : 0;
    __syncthreads();
    if (t < BSZ) {
      x += tm;
      lscan[t] = x;
    }
    __syncthreads();
  }
  if (t < BSZ) {
    int node = node0 + t;
    lcur[t] = beg + lscan[t] - ldeg[t];  // exclusive start (global)
    if (node < n) {
      deg[node] = ldeg[t];
      row_ptr[node + 1] = beg + lscan[t];
      if (node == 0) row_ptr[0] = 0;
    }
  }
  __syncthreads();
  for (int i = beg + t; i < end; i += 256) {
    unsigned p = pairs[i];
    int pos = atomicAdd(&lcur[p >> 18], 1);
    src_sorted[pos] = (int)(p & 0x3FFFFu);
  }
}

// ------------------------------------------------------- f16 preprocessing
__global__ __launch_bounds__(256) void convert_features(const float* __restrict__ f,
                                                        _Float16* __restrict__ X, int n) {
  int idx = blockIdx.x * 256 + threadIdx.x;
  int total = n * 32;
  if (idx >= total) return;
  int node = idx >> 5;
  int c4 = (idx & 31) * 4;
  float4 v = *(const float4*)(f + (size_t)node * 128 + c4);
  _Float16* o = X + (size_t)node * 256 + c4;
  o[0] = (_Float16)v.x;
  o[1] = (_Float16)v.y;
  o[2] = (_Float16)v.z;
  o[3] = (_Float16)v.w;
}

__global__ __launch_bounds__(256) void build_wt(const float* __restrict__ Ws,
                                                const float* __restrict__ Wn,
                                                _Float16* __restrict__ Wt, int NOUT) {
  int idx = blockIdx.x * 256 + threadIdx.x;
  if (idx >= NOUT * 256) return;
  int nn = idx >> 8;
  int k = idx & 255;
  float v = (k < 128) ? Ws[(size_t)k * NOUT + nn] : Wn[(size_t)(k - 128) * NOUT + nn];
  Wt[(size_t)nn * 256 + k] = (_Float16)v;
}

// ---------------------------------------------------------- mean aggregation
__global__ __launch_bounds__(256) void aggregate_f16(
    const _Float16* __restrict__ X, const int* __restrict__ row_ptr,
    const int* __restrict__ src_sorted, const int* __restrict__ deg,
    _Float16* __restrict__ Xout, int n) {
  int gid = blockIdx.x * 256 + threadIdx.x;
  int node = gid >> 6;
  int lane = gid & 63;
  if (node >= n) return;
  int beg = row_ptr[node];
  int end = row_ptr[node + 1];
  float ax = 0.f, ay = 0.f;
  int e = beg;
  for (; e + 4 <= end; e += 4) {
    int s0 = src_sorted[e + 0];
    int s1 = src_sorted[e + 1];
    int s2 = src_sorted[e + 2];
    int s3 = src_sorted[e + 3];
    f16x2 v0 = *(const f16x2*)(X + (size_t)s0 * 256 + lane * 2);
    f16x2 v1 = *(const f16x2*)(X + (size_t)s1 * 256 + lane * 2);
    f16x2 v2 = *(const f16x2*)(X + (size_t)s2 * 256 + lane * 2);
    f16x2 v3 = *(const f16x2*)(X + (size_t)s3 * 256 + lane * 2);
    ax += (float)v0[0] + (float)v1[0] + (float)v2[0] + (float)v3[0];
    ay += (float)v0[1] + (float)v1[1] + (float)v2[1] + (float)v3[1];
  }
  for (; e < end; ++e) {
    int s0 = src_sorted[e];
    f16x2 v0 = *(const f16x2*)(X + (size_t)s0 * 256 + lane * 2);
    ax += (float)v0[0];
    ay += (float)v0[1];
  }
  float inv = 1.0f / fmaxf((float)deg[node], 1.0f);
  f16x2 o;
  o[0] = (_Float16)(ax * inv);
  o[1] = (_Float16)(ay * inv);
  *(f16x2*)(Xout + (size_t)node * 256 + 128 + lane * 2) = o;
}

// ------------------------------------------------------------------- GEMM
template <int NOUT, bool RELU, bool FINAL>
__global__ __launch_bounds__(256) void gemm_mfma(
    const _Float16* __restrict__ X, const _Float16* __restrict__ Wt,
    const float* __restrict__ bias, _Float16* __restrict__ outX,
    float* __restrict__ outF, int n) {
  constexpr int CW = NOUT / 2;   // cols per wave
  constexpr int CF = CW / 16;    // col frags per wave
  __shared__ _Float16 Xs[128][72];    // +8 pad: frag stride 144B -> <=2-way
  __shared__ _Float16 Wc[NOUT][72];

  int tid = threadIdx.x;
  int lane = tid & 63;
  int wid = tid >> 6;
  int wr = wid >> 1;
  int wc = wid & 1;
  int node0 = blockIdx.x * 128;

  f32x4 acc[4][CF];
#pragma unroll
  for (int i = 0; i < 4; ++i)
#pragma unroll
    for (int j = 0; j < CF; ++j) acc[i][j] = {0.f, 0.f, 0.f, 0.f};

#pragma unroll
  for (int c = 0; c < 4; ++c) {
    int k0 = c * 64;
#pragma unroll
    for (int i = 0; i < 4; ++i) {
      int idx = i * 256 + tid;
      int r = idx >> 3;
      int o = (idx & 7) * 8;
      f16x8 v;
#pragma unroll
      for (int z = 0; z < 8; ++z) v[z] = (_Float16)0.f;
      int node = node0 + r;
      if (node < n) v = *(const f16x8*)(X + (size_t)node * 256 + k0 + o);
      *(f16x8*)&Xs[r][o] = v;
    }
#pragma unroll
    for (int i = 0; i < NOUT / 32; ++i) {
      int idx = i * 256 + tid;
      int r = idx >> 3;
      int o = (idx & 7) * 8;
      *(f16x8*)&Wc[r][o] = *(const f16x8*)(Wt + (size_t)r * 256 + k0 + o);
    }
    __syncthreads();
#pragma unroll
    for (int ks = 0; ks < 2; ++ks) {
      int kk = ks * 32 + (lane >> 4) * 8;
      f16x8 a[4], b[CF];
#pragma unroll
      for (int i = 0; i < 4; ++i)
        a[i] = *(const f16x8*)&Xs[wr * 64 + i * 16 + (lane & 15)][kk];
#pragma unroll
      for (int j = 0; j < CF; ++j)
        b[j] = *(const f16x8*)&Wc[wc * CW + j * 16 + (lane & 15)][kk];
#pragma unroll
      for (int i = 0; i < 4; ++i)
#pragma unroll
        for (int j = 0; j < CF; ++j)
          acc[i][j] = __builtin_amdgcn_mfma_f32_16x16x32_f16(a[i], b[j], acc[i][j], 0, 0, 0);
    }
    __syncthreads();
  }

#pragma unroll
  for (int j = 0; j < CF; ++j) {
    int col = wc * CW + j * 16 + (lane & 15);
    float bv = bias[col];
#pragma unroll
    for (int i = 0; i < 4; ++i) {
#pragma unroll
      for (int q = 0; q < 4; ++q) {
        int row = wr * 64 + i * 16 + (lane >> 4) * 4 + q;
        int node = node0 + row;
        if (node < n) {
          float v = acc[i][j][q] + bv;
          if (RELU) v = fmaxf(v, 0.f);
          if (FINAL)
            outF[(size_t)node * NOUT + col] = v;
          else
            outX[(size_t)node * 256 + col] = (_Float16)v;
        }
      }
    }
  }
}

// ------------------------------------------------------------------ launch
extern "C" void kernel_launch(void* const* d_in, const int* in_sizes, int n_in,
                              void* d_out, int out_size, void* d_ws, size_t ws_size,
                              hipStream_t stream) {
  const float* features = (const float*)d_in[0];
  const int* src = (const int*)d_in[1];
  const int* dst = (const int*)d_in[2];
  const float* Ws0 = (const float*)d_in[3];
  const float* Wn0 = (const float*)d_in[4];
  const float* b0 = (const float*)d_in[5];
  const float* Ws1 = (const float*)d_in[6];
  const float* Wn1 = (const float*)d_in[7];
  const float* b1 = (const float*)d_in[8];
  const float* Ws2 = (const float*)d_in[9];
  const float* Wn2 = (const float*)d_in[10];
  const float* b2 = (const float*)d_in[11];

  const int n = in_sizes[0] / 128;
  const int n_edges = in_sizes[1];
  const int nbk = (n + BSZ - 1) >> BSHIFT;          // 782 buckets
  const int nblk = (n_edges + EPB - 1) / EPB;       // 98 sort blocks

  char* ws = (char*)d_ws;
  size_t off = 0;
  auto alloc = [&](size_t bytes) -> void* {
    void* p = ws + off;
    off += (bytes + 255) & ~(size_t)255;
    return p;
  };
  int* hist_pb = (int*)alloc((size_t)nblk * nbk * 4);
  int* btot = (int*)alloc((size_t)nbk * 4);
  int* bbase = (int*)alloc(((size_t)nbk + 1) * 4);
  unsigned* pairs = (unsigned*)alloc((size_t)n_edges * 4);
  int* deg = (int*)alloc((size_t)n * 4);
  int* row_ptr = (int*)alloc(((size_t)n + 1) * 4);
  int* src_sorted = (int*)alloc((size_t)n_edges * 4);
  _Float16* XA = (_Float16*)alloc((size_t)n * 256 * 2);
  _Float16* XB = (_Float16*)alloc((size_t)n * 256 * 2);
  _Float16* Wt0 = (_Float16*)alloc((size_t)128 * 256 * 2);
  _Float16* Wt1 = (_Float16*)alloc((size_t)128 * 256 * 2);
  _Float16* Wt2 = (_Float16*)alloc((size_t)64 * 256 * 2);

  int nbkb = (nbk + 255) / 256;
  histA<<<nblk, 256, 0, stream>>>(dst, hist_pb, n_edges, nbk);
  sumB1<<<nbkb, 256, 0, stream>>>(hist_pb, btot, nblk, nbk);
  scanB2<<<1, 1024, 0, stream>>>(btot, bbase, nbk);
  offsB3<<<nbkb, 256, 0, stream>>>(hist_pb, bbase, nblk, nbk);
  scatC<<<nblk, 256, 0, stream>>>(src, dst, hist_pb, pairs, n_edges, nbk);
  finalD<<<nbk, 256, 0, stream>>>(pairs, bbase, deg, row_ptr, src_sorted, n, nbk);

  convert_features<<<(n * 32 + 255) / 256, 256, 0, stream>>>(features, XA, n);
  build_wt<<<(128 * 256 + 255) / 256, 256, 0, stream>>>(Ws0, Wn0, Wt0, 128);
  build_wt<<<(128 * 256 + 255) / 256, 256, 0, stream>>>(Ws1, Wn1, Wt1, 128);
  build_wt<<<(64 * 256 + 255) / 256, 256, 0, stream>>>(Ws2, Wn2, Wt2, 64);

  int agg_blocks = (int)(((size_t)n * 64 + 255) / 256);
  int gemm_blocks = (n + 127) / 128;

  aggregate_f16<<<agg_blocks, 256, 0, stream>>>(XA, row_ptr, src_sorted, deg, XA, n);
  gemm_mfma<128, true, false><<<gemm_blocks, 256, 0, stream>>>(XA, Wt0, b0, XB, nullptr, n);
  aggregate_f16<<<agg_blocks, 256, 0, stream>>>(XB, row_ptr, src_sorted, deg, XB, n);
  gemm_mfma<128, true, false><<<gemm_blocks, 256, 0, stream>>>(XB, Wt1, b1, XA, nullptr, n);
  aggregate_f16<<<agg_blocks, 256, 0, stream>>>(XA, row_ptr, src_sorted, deg, XA, n);
  gemm_mfma<64, false, true><<<gemm_blocks, 256, 0, stream>>>(XA, Wt2, b2, nullptr, (float*)d_out, n);
}

// Round 6
// 538.426 us; speedup vs baseline: 2.0958x; 1.0201x over previous
//
#include <hip/hip_runtime.h>

typedef _Float16 f16x8 __attribute__((ext_vector_type(8)));
typedef _Float16 f16x4 __attribute__((ext_vector_type(4)));
typedef _Float16 f16x2 __attribute__((ext_vector_type(2)));
typedef float f32x4 __attribute__((ext_vector_type(4)));

// GraphSAGE 3-layer, mean aggregator, eval mode. f16 storage + MFMA GEMM.
// CSR build via two-level block-ranged counting sort (R5, unchanged).
// R6: aggregate restructured for 2x memory-level parallelism:
//   lane = (edge-slot l>>5, feature-quad l&31); one VMEM instr covers 2 src rows;
//   unroll-4 main loop keeps 8 edges (2KB) in flight; __shfl_xor(32) reduce.

#define BSHIFT 7
#define BSZ 128           // nodes per bucket
#define EPB 16384         // edges per block in passes A/C

// ------------------------------------------------------------- sort pass A
__global__ __launch_bounds__(256) void histA(const int* __restrict__ dst,
                                             int* __restrict__ hist_pb,
                                             int n_edges, int nbk) {
  __shared__ unsigned lh[1024];
  for (int i = threadIdx.x; i < nbk; i += 256) lh[i] = 0;
  __syncthreads();
  int base = blockIdx.x * EPB;
  for (int i = threadIdx.x; i < EPB; i += 256) {
    int e = base + i;
    if (e < n_edges) atomicAdd(&lh[dst[e] >> BSHIFT], 1u);
  }
  __syncthreads();
  for (int i = threadIdx.x; i < nbk; i += 256)
    hist_pb[(size_t)blockIdx.x * nbk + i] = (int)lh[i];
}

// ------------------------------------------------------------- sort pass B
__global__ __launch_bounds__(256) void sumB1(const int* __restrict__ hist_pb,
                                             int* __restrict__ btot, int nblk, int nbk) {
  int b = blockIdx.x * 256 + threadIdx.x;
  if (b >= nbk) return;
  int s = 0;
  for (int k = 0; k < nblk; ++k) s += hist_pb[(size_t)k * nbk + b];
  btot[b] = s;
}

__global__ __launch_bounds__(1024) void scanB2(const int* __restrict__ btot,
                                               int* __restrict__ bbase, int nbk) {
  __shared__ int buf[1024];
  int t = threadIdx.x;
  int v = (t < nbk) ? btot[t] : 0;
  int x = v;
  buf[t] = x;
  __syncthreads();
#pragma unroll
  for (int off = 1; off < 1024; off <<= 1) {
    int tm = (t >= off) ? buf[t - off] : 0;
    __syncthreads();
    x += tm;
    buf[t] = x;
    __syncthreads();
  }
  if (t < nbk) bbase[t] = x - v;          // exclusive
  if (t == nbk - 1) bbase[nbk] = x;       // total edge count
}

__global__ __launch_bounds__(256) void offsB3(int* __restrict__ hist_pb,
                                              const int* __restrict__ bbase,
                                              int nblk, int nbk) {
  int b = blockIdx.x * 256 + threadIdx.x;
  if (b >= nbk) return;
  int run = bbase[b];
  for (int k = 0; k < nblk; ++k) {
    int t = hist_pb[(size_t)k * nbk + b];
    hist_pb[(size_t)k * nbk + b] = run;
    run += t;
  }
}

// ------------------------------------------------------------- sort pass C
__global__ __launch_bounds__(256) void scatC(const int* __restrict__ src,
                                             const int* __restrict__ dst,
                                             const int* __restrict__ hist_pb,
                                             unsigned* __restrict__ pairs,
                                             int n_edges, int nbk) {
  __shared__ unsigned lofs[1024];
  for (int i = threadIdx.x; i < nbk; i += 256)
    lofs[i] = (unsigned)hist_pb[(size_t)blockIdx.x * nbk + i];
  __syncthreads();
  int base = blockIdx.x * EPB;
  for (int i = threadIdx.x; i < EPB; i += 256) {
    int e = base + i;
    if (e < n_edges) {
      int d = dst[e];
      unsigned pos = atomicAdd(&lofs[d >> BSHIFT], 1u);
      pairs[pos] = ((unsigned)(d & (BSZ - 1)) << 18) | (unsigned)src[e];
    }
  }
}

// ------------------------------------------------------------- sort pass D
__global__ __launch_bounds__(256) void finalD(const unsigned* __restrict__ pairs,
                                              const int* __restrict__ bbase,
                                              int* __restrict__ deg,
                                              int* __restrict__ row_ptr,
                                              int* __restrict__ src_sorted,
                                              int n, int nbk) {
  __shared__ int ldeg[BSZ];
  __shared__ int lscan[BSZ];
  __shared__ int lcur[BSZ];
  int b = blockIdx.x;
  int t = threadIdx.x;
  int node0 = b << BSHIFT;
  int beg = bbase[b], end = bbase[b + 1];
  if (t < BSZ) ldeg[t] = 0;
  __syncthreads();
  for (int i = beg + t; i < end; i += 256) atomicAdd(&ldeg[pairs[i] >> 18], 1);
  __syncthreads();
  int x = (t < BSZ) ? ldeg[t] : 0;
  if (t < BSZ) lscan[t] = x;
  __syncthreads();
#pragma unroll
  for (int off = 1; off < BSZ; off <<= 1) {
    int tm = (t >= off && t < BSZ) ? lscan[t - off] : 0;
    __syncthreads();
    if (t < BSZ) {
      x += tm;
      lscan[t] = x;
    }
    __syncthreads();
  }
  if (t < BSZ) {
    int node = node0 + t;
    lcur[t] = beg + lscan[t] - ldeg[t];  // exclusive start (global)
    if (node < n) {
      deg[node] = ldeg[t];
      row_ptr[node + 1] = beg + lscan[t];
      if (node == 0) row_ptr[0] = 0;
    }
  }
  __syncthreads();
  for (int i = beg + t; i < end; i += 256) {
    unsigned p = pairs[i];
    int pos = atomicAdd(&lcur[p >> 18], 1);
    src_sorted[pos] = (int)(p & 0x3FFFFu);
  }
}

// ------------------------------------------------------- f16 preprocessing
__global__ __launch_bounds__(256) void convert_features(const float* __restrict__ f,
                                                        _Float16* __restrict__ X, int n) {
  int idx = blockIdx.x * 256 + threadIdx.x;
  int total = n * 32;
  if (idx >= total) return;
  int node = idx >> 5;
  int c4 = (idx & 31) * 4;
  float4 v = *(const float4*)(f + (size_t)node * 128 + c4);
  _Float16* o = X + (size_t)node * 256 + c4;
  o[0] = (_Float16)v.x;
  o[1] = (_Float16)v.y;
  o[2] = (_Float16)v.z;
  o[3] = (_Float16)v.w;
}

__global__ __launch_bounds__(256) void build_wt(const float* __restrict__ Ws,
                                                const float* __restrict__ Wn,
                                                _Float16* __restrict__ Wt, int NOUT) {
  int idx = blockIdx.x * 256 + threadIdx.x;
  if (idx >= NOUT * 256) return;
  int nn = idx >> 8;
  int k = idx & 255;
  float v = (k < 128) ? Ws[(size_t)k * NOUT + nn] : Wn[(size_t)(k - 128) * NOUT + nn];
  Wt[(size_t)nn * 256 + k] = (_Float16)v;
}

// ---------------------------------------------------------- mean aggregation
// Wave per dst node. lane = (edge-slot es = l>>5, feature-quad fh = l&31).
// One VMEM instr = 2 src rows (es halves) x 32 lanes x f16x4(8B) = 512B.
// Main loop: 8 edges / 4 VMEM (2KB) in flight. fp32 accumulate.
// Epilogue: acc += shfl_xor(acc,32); es==0 half writes f16x4.
__global__ __launch_bounds__(256) void aggregate_f16(
    const _Float16* __restrict__ X, const int* __restrict__ row_ptr,
    const int* __restrict__ src_sorted, const int* __restrict__ deg,
    _Float16* __restrict__ Xout, int n) {
  int gid = blockIdx.x * 256 + threadIdx.x;
  int node = gid >> 6;
  if (node >= n) return;
  int lane = threadIdx.x & 63;
  int fh = lane & 31;   // feature quad -> features [fh*4, fh*4+4)
  int es = lane >> 5;   // edge slot
  int beg = row_ptr[node];
  int end = row_ptr[node + 1];
  float a0 = 0.f, a1 = 0.f, a2 = 0.f, a3 = 0.f;
  int e = beg;
  for (; e + 8 <= end; e += 8) {
    int s0 = src_sorted[e + 0 + es];
    int s1 = src_sorted[e + 2 + es];
    int s2 = src_sorted[e + 4 + es];
    int s3 = src_sorted[e + 6 + es];
    f16x4 v0 = *(const f16x4*)(X + (size_t)s0 * 256 + fh * 4);
    f16x4 v1 = *(const f16x4*)(X + (size_t)s1 * 256 + fh * 4);
    f16x4 v2 = *(const f16x4*)(X + (size_t)s2 * 256 + fh * 4);
    f16x4 v3 = *(const f16x4*)(X + (size_t)s3 * 256 + fh * 4);
    a0 += (float)v0[0] + (float)v1[0] + (float)v2[0] + (float)v3[0];
    a1 += (float)v0[1] + (float)v1[1] + (float)v2[1] + (float)v3[1];
    a2 += (float)v0[2] + (float)v1[2] + (float)v2[2] + (float)v3[2];
    a3 += (float)v0[3] + (float)v1[3] + (float)v2[3] + (float)v3[3];
  }
  for (; e < end; e += 2) {
    if (e + es < end) {
      int s = src_sorted[e + es];
      f16x4 v = *(const f16x4*)(X + (size_t)s * 256 + fh * 4);
      a0 += (float)v[0];
      a1 += (float)v[1];
      a2 += (float)v[2];
      a3 += (float)v[3];
    }
  }
  // fold the two edge-slot halves (lane ^ 32 holds same feature quad)
  a0 += __shfl_xor(a0, 32);
  a1 += __shfl_xor(a1, 32);
  a2 += __shfl_xor(a2, 32);
  a3 += __shfl_xor(a3, 32);
  if (es == 0) {
    float inv = 1.0f / fmaxf((float)(end - beg), 1.0f);
    f16x4 o;
    o[0] = (_Float16)(a0 * inv);
    o[1] = (_Float16)(a1 * inv);
    o[2] = (_Float16)(a2 * inv);
    o[3] = (_Float16)(a3 * inv);
    *(f16x4*)(Xout + (size_t)node * 256 + 128 + fh * 4) = o;
  }
}

// ------------------------------------------------------------------- GEMM
template <int NOUT, bool RELU, bool FINAL>
__global__ __launch_bounds__(256) void gemm_mfma(
    const _Float16* __restrict__ X, const _Float16* __restrict__ Wt,
    const float* __restrict__ bias, _Float16* __restrict__ outX,
    float* __restrict__ outF, int n) {
  constexpr int CW = NOUT / 2;   // cols per wave
  constexpr int CF = CW / 16;    // col frags per wave
  __shared__ _Float16 Xs[128][72];    // +8 pad: frag stride 144B -> <=2-way
  __shared__ _Float16 Wc[NOUT][72];

  int tid = threadIdx.x;
  int lane = tid & 63;
  int wid = tid >> 6;
  int wr = wid >> 1;
  int wc = wid & 1;
  int node0 = blockIdx.x * 128;

  f32x4 acc[4][CF];
#pragma unroll
  for (int i = 0; i < 4; ++i)
#pragma unroll
    for (int j = 0; j < CF; ++j) acc[i][j] = {0.f, 0.f, 0.f, 0.f};

#pragma unroll
  for (int c = 0; c < 4; ++c) {
    int k0 = c * 64;
#pragma unroll
    for (int i = 0; i < 4; ++i) {
      int idx = i * 256 + tid;
      int r = idx >> 3;
      int o = (idx & 7) * 8;
      f16x8 v;
#pragma unroll
      for (int z = 0; z < 8; ++z) v[z] = (_Float16)0.f;
      int node = node0 + r;
      if (node < n) v = *(const f16x8*)(X + (size_t)node * 256 + k0 + o);
      *(f16x8*)&Xs[r][o] = v;
    }
#pragma unroll
    for (int i = 0; i < NOUT / 32; ++i) {
      int idx = i * 256 + tid;
      int r = idx >> 3;
      int o = (idx & 7) * 8;
      *(f16x8*)&Wc[r][o] = *(const f16x8*)(Wt + (size_t)r * 256 + k0 + o);
    }
    __syncthreads();
#pragma unroll
    for (int ks = 0; ks < 2; ++ks) {
      int kk = ks * 32 + (lane >> 4) * 8;
      f16x8 a[4], b[CF];
#pragma unroll
      for (int i = 0; i < 4; ++i)
        a[i] = *(const f16x8*)&Xs[wr * 64 + i * 16 + (lane & 15)][kk];
#pragma unroll
      for (int j = 0; j < CF; ++j)
        b[j] = *(const f16x8*)&Wc[wc * CW + j * 16 + (lane & 15)][kk];
#pragma unroll
      for (int i = 0; i < 4; ++i)
#pragma unroll
        for (int j = 0; j < CF; ++j)
          acc[i][j] = __builtin_amdgcn_mfma_f32_16x16x32_f16(a[i], b[j], acc[i][j], 0, 0, 0);
    }
    __syncthreads();
  }

#pragma unroll
  for (int j = 0; j < CF; ++j) {
    int col = wc * CW + j * 16 + (lane & 15);
    float bv = bias[col];
#pragma unroll
    for (int i = 0; i < 4; ++i) {
#pragma unroll
      for (int q = 0; q < 4; ++q) {
        int row = wr * 64 + i * 16 + (lane >> 4) * 4 + q;
        int node = node0 + row;
        if (node < n) {
          float v = acc[i][j][q] + bv;
          if (RELU) v = fmaxf(v, 0.f);
          if (FINAL)
            outF[(size_t)node * NOUT + col] = v;
          else
            outX[(size_t)node * 256 + col] = (_Float16)v;
        }
      }
    }
  }
}

// ------------------------------------------------------------------ launch
extern "C" void kernel_launch(void* const* d_in, const int* in_sizes, int n_in,
                              void* d_out, int out_size, void* d_ws, size_t ws_size,
                              hipStream_t stream) {
  const float* features = (const float*)d_in[0];
  const int* src = (const int*)d_in[1];
  const int* dst = (const int*)d_in[2];
  const float* Ws0 = (const float*)d_in[3];
  const float* Wn0 = (const float*)d_in[4];
  const float* b0 = (const float*)d_in[5];
  const float* Ws1 = (const float*)d_in[6];
  const float* Wn1 = (const float*)d_in[7];
  const float* b1 = (const float*)d_in[8];
  const float* Ws2 = (const float*)d_in[9];
  const float* Wn2 = (const float*)d_in[10];
  const float* b2 = (const float*)d_in[11];

  const int n = in_sizes[0] / 128;
  const int n_edges = in_sizes[1];
  const int nbk = (n + BSZ - 1) >> BSHIFT;          // 782 buckets
  const int nblk = (n_edges + EPB - 1) / EPB;       // 98 sort blocks

  char* ws = (char*)d_ws;
  size_t off = 0;
  auto alloc = [&](size_t bytes) -> void* {
    void* p = ws + off;
    off += (bytes + 255) & ~(size_t)255;
    return p;
  };
  int* hist_pb = (int*)alloc((size_t)nblk * nbk * 4);
  int* btot = (int*)alloc((size_t)nbk * 4);
  int* bbase = (int*)alloc(((size_t)nbk + 1) * 4);
  unsigned* pairs = (unsigned*)alloc((size_t)n_edges * 4);
  int* deg = (int*)alloc((size_t)n * 4);
  int* row_ptr = (int*)alloc(((size_t)n + 1) * 4);
  int* src_sorted = (int*)alloc((size_t)n_edges * 4);
  _Float16* XA = (_Float16*)alloc((size_t)n * 256 * 2);
  _Float16* XB = (_Float16*)alloc((size_t)n * 256 * 2);
  _Float16* Wt0 = (_Float16*)alloc((size_t)128 * 256 * 2);
  _Float16* Wt1 = (_Float16*)alloc((size_t)128 * 256 * 2);
  _Float16* Wt2 = (_Float16*)alloc((size_t)64 * 256 * 2);

  int nbkb = (nbk + 255) / 256;
  histA<<<nblk, 256, 0, stream>>>(dst, hist_pb, n_edges, nbk);
  sumB1<<<nbkb, 256, 0, stream>>>(hist_pb, btot, nblk, nbk);
  scanB2<<<1, 1024, 0, stream>>>(btot, bbase, nbk);
  offsB3<<<nbkb, 256, 0, stream>>>(hist_pb, bbase, nblk, nbk);
  scatC<<<nblk, 256, 0, stream>>>(src, dst, hist_pb, pairs, n_edges, nbk);
  finalD<<<nbk, 256, 0, stream>>>(pairs, bbase, deg, row_ptr, src_sorted, n, nbk);

  convert_features<<<(n * 32 + 255) / 256, 256, 0, stream>>>(features, XA, n);
  build_wt<<<(128 * 256 + 255) / 256, 256, 0, stream>>>(Ws0, Wn0, Wt0, 128);
  build_wt<<<(128 * 256 + 255) / 256, 256, 0, stream>>>(Ws1, Wn1, Wt1, 128);
  build_wt<<<(64 * 256 + 255) / 256, 256, 0, stream>>>(Ws2, Wn2, Wt2, 64);

  int agg_blocks = (int)(((size_t)n * 64 + 255) / 256);
  int gemm_blocks = (n + 127) / 128;

  aggregate_f16<<<agg_blocks, 256, 0, stream>>>(XA, row_ptr, src_sorted, deg, XA, n);
  gemm_mfma<128, true, false><<<gemm_blocks, 256, 0, stream>>>(XA, Wt0, b0, XB, nullptr, n);
  aggregate_f16<<<agg_blocks, 256, 0, stream>>>(XB, row_ptr, src_sorted, deg, XB, n);
  gemm_mfma<128, true, false><<<gemm_blocks, 256, 0, stream>>>(XB, Wt1, b1, XA, nullptr, n);
  aggregate_f16<<<agg_blocks, 256, 0, stream>>>(XA, row_ptr, src_sorted, deg, XA, n);
  gemm_mfma<64, false, true><<<gemm_blocks, 256, 0, stream>>>(XA, Wt2, b2, nullptr, (float*)d_out, n);
}